// Round 1
// baseline (125.821 us; speedup 1.0000x reference)
//
#include <hip/hip_runtime.h>
#include <hip/hip_bf16.h>
#include <math.h>

// Dims: B=8, T=1048576, V=257, E=8, C=128, K=512, S=512, N=64
// GEMM view: M=16384, Kdim=4096, Ncols=256.
// Fully fused: col tile nt = [w1 ch 32nt..+32 | w2 ch 32nt..+32] so each lane
// holds matching (c1,c2) accumulators; epilogue does bias+gate+patch-max
// in-register and writes d_out directly. No Cbuf, no reduce kernel.

typedef __bf16 bf16x8 __attribute__((ext_vector_type(8)));
typedef float  f32x4  __attribute__((ext_vector_type(4)));

// ---------------- ws layout ----------------
// [0, 2MB)    : Wp bf16 [nt=4][s'=16][t=8][q=4][n=64][e=8]  (byte = s'*32+q*8+t)
// [2MB, +8KB) : emb bf16 [257][8]
#define WS_WP_OFF   0
#define WS_EMB_OFF  (2u << 20)

__device__ __forceinline__ void load_lds16(const void* g, void* l) {
    __builtin_amdgcn_global_load_lds(
        (const __attribute__((address_space(1))) void*)g,
        (__attribute__((address_space(3))) void*)l,
        16, 0, 0);
}

// ---------------------------------------------------------------------------
// prep: coalesced LDS-transpose weight pack + emb bf16 table.
// cb = nt*2 + nhalf: nhalf=0 -> w1 channels [32nt,32nt+32), nhalf=1 -> w2 same.
// ---------------------------------------------------------------------------
__global__ void prep_kernel(const float* __restrict__ w1,
                            const float* __restrict__ w2,
                            const float* __restrict__ emb,
                            uint4* __restrict__ Wp4,
                            __bf16* __restrict__ embp) {
    int bid = blockIdx.x;
    int tid = threadIdx.x;
    if (bid < 128) {
        __shared__ __bf16 lds[8192];   // [(q*8+t)*32 + cl]*8 + e
        int cb = bid & 7;
        int sB = bid >> 3;
        int nt = cb >> 1, nhalf = cb & 1;
        const float* wsrc = (nhalf ? w2 : w1) + ((size_t)(nt << 5) << 12);
        int j4  = tid & 7;
        int pr0 = tid >> 3;
#pragma unroll
        for (int p = 0; p < 8; ++p) {
            int pair = p * 32 + pr0;          // 0..255 = (cl, e)
            int cl = pair >> 3, e = pair & 7;
            const float4 v = *(const float4*)(wsrc + ((size_t)cl << 12) + (e << 9) + (sB << 5) + (j4 << 2));
            float vv[4] = {v.x, v.y, v.z, v.w};
#pragma unroll
            for (int jj = 0; jj < 4; ++jj) {
                int j = (j4 << 2) + jj;        // byte_local
                int qq = j >> 3, tt = j & 7;
                lds[(((qq << 3) + tt) * 32 + cl) * 8 + e] = (__bf16)vv[jj];
            }
        }
        __syncthreads();
        const uint4* l4 = (const uint4*)lds;
        int base = (nt << 15) + (sB << 11) + (nhalf << 5);   // uint4 units
#pragma unroll
        for (int it = 0; it < 4; ++it) {
            int idx = it * 256 + tid;                         // 0..1023
            int qq = idx >> 8, tt = (idx >> 5) & 7, w = idx & 31;
            Wp4[base + (tt << 8) + (qq << 6) + w] = l4[idx];
        }
    } else {
        for (int i = tid; i < 2056; i += 256) embp[i] = (__bf16)emb[i];
    }
}

// ---------------------------------------------------------------------------
// gemm+epilogue: BM=256, BN=64, 4 waves, wave-tile 64x64 (4rg x 4nf), full K
// (16 steps). Double-buffered B staging (global_load_lds w=16), x prefetch,
// emb in LDS. Epilogue: gate = (c1+b1)*sigmoid(c2+b2), per-patch max (32 rows)
// via in-register max + 2x shfl_xor across q-groups, direct out write.
// Grid 256 = 64 mt x 4 nt, bid&7 = XCD so the 4 nt-blocks sharing an x panel
// land on one XCD (L2 dedup of the 4x x re-read).
// ---------------------------------------------------------------------------
__global__ __launch_bounds__(256, 1)
void gemm_kernel(const int* __restrict__ x,
                 const __bf16* __restrict__ Wp,
                 const uint4* __restrict__ embp,
                 const float* __restrict__ b1,
                 const float* __restrict__ b2,
                 float* __restrict__ out) {
    __shared__ uint4 ldsB[2][2048];   // 2 x 32KB: [t=8][q=4][n=64][e=8]
    __shared__ uint4 embl[257];

    const int tid  = threadIdx.x;
    const int wave = tid >> 6;
    const int lane = tid & 63;
    const int q    = lane >> 4;
    const int nl   = lane & 15;

    for (int i = tid; i < 257; i += 256) embl[i] = embp[i];

    const int bid = blockIdx.x;
    const int mt = ((bid >> 5) << 3) | (bid & 7);
    const int nt = (bid >> 3) & 3;
    const int m0 = mt << 8;
    const int rA = m0 + (wave << 6) + nl;
    const char* WpBase = (const char*)Wp + ((size_t)nt << 19);

    const int* xp[4];
#pragma unroll
    for (int rg = 0; rg < 4; ++rg)
        xp[rg] = x + (size_t)(rA + (rg << 4)) * 512 + (q << 3);

    int4 xc[4][2];
#pragma unroll
    for (int rg = 0; rg < 4; ++rg) {
        xc[rg][0] = *(const int4*)xp[rg];
        xc[rg][1] = *(const int4*)(xp[rg] + 4);
    }
    {
        const char* src = WpBase + tid * 16;
        char* dst = (char*)&ldsB[0][0] + tid * 16;
#pragma unroll
        for (int i = 0; i < 8; ++i) load_lds16(src + i * 4096, dst + i * 4096);
    }
    __syncthreads();

    f32x4 acc[4][4] = {};

    for (int sp = 0; sp < 16; ++sp) {
        const int buf = sp & 1;
        if (sp + 1 < 16) {   // stage next step into other buffer (async)
            const char* src = WpBase + ((size_t)(sp + 1) << 15) + tid * 16;
            char* dst = (char*)&ldsB[buf ^ 1][0] + tid * 16;
#pragma unroll
            for (int i = 0; i < 8; ++i) load_lds16(src + i * 4096, dst + i * 4096);
        }
        int idx[4][8];
#pragma unroll
        for (int rg = 0; rg < 4; ++rg) {
            idx[rg][0] = xc[rg][0].x; idx[rg][1] = xc[rg][0].y;
            idx[rg][2] = xc[rg][0].z; idx[rg][3] = xc[rg][0].w;
            idx[rg][4] = xc[rg][1].x; idx[rg][5] = xc[rg][1].y;
            idx[rg][6] = xc[rg][1].z; idx[rg][7] = xc[rg][1].w;
        }
        const int spn = (sp + 1 < 16) ? sp + 1 : sp;   // x prefetch
#pragma unroll
        for (int rg = 0; rg < 4; ++rg) {
            const int* p = xp[rg] + (spn << 5);
            xc[rg][0] = *(const int4*)p;
            xc[rg][1] = *(const int4*)(p + 4);
        }
        const char* Bbase = (const char*)&ldsB[buf][0] + (q << 10) + (nl << 4);
#pragma unroll
        for (int t = 0; t < 8; ++t) {
            bf16x8 a[4];
#pragma unroll
            for (int rg = 0; rg < 4; ++rg)
                a[rg] = *reinterpret_cast<const bf16x8*>(&embl[idx[rg][t]]);
#pragma unroll
            for (int nf = 0; nf < 4; ++nf) {
                bf16x8 b = *reinterpret_cast<const bf16x8*>(Bbase + (t << 12) + (nf << 8));
#pragma unroll
                for (int rg = 0; rg < 4; ++rg)
                    acc[rg][nf] = __builtin_amdgcn_mfma_f32_16x16x32_bf16(a[rg], b, acc[rg][nf], 0, 0, 0);
            }
        }
        __syncthreads();
    }

    // ---- fused epilogue ----
    // acc[rg][nf][i]: row = m0 + wave*64 + rg*16 + q*4 + i
    //   nf in {0,1}: c1 of channel ch = nt*32 + nf*16 + nl; nf+2: c2 of same ch.
    // patch (32 rows) = mt*8 + wave*2 + (rg>>1); all 32 rows covered by
    // (rg&1, q, i) -> per-lane max over (rg&1, i), then shfl_xor 16/32 over q.
    float bb1[2], bb2[2];
#pragma unroll
    for (int nf = 0; nf < 2; ++nf) {
        int ch = (nt << 5) + (nf << 4) + nl;
        bb1[nf] = b1[ch];
        bb2[nf] = b2[ch];
    }
#pragma unroll
    for (int ph = 0; ph < 2; ++ph) {
#pragma unroll
        for (int nf = 0; nf < 2; ++nf) {
            float v = -INFINITY;
#pragma unroll
            for (int rh = 0; rh < 2; ++rh) {
                int rg = (ph << 1) + rh;
#pragma unroll
                for (int i = 0; i < 4; ++i) {
                    float c1 = acc[rg][nf][i] + bb1[nf];
                    float c2 = acc[rg][nf + 2][i] + bb2[nf];
                    float g = c1 * (1.0f / (1.0f + __expf(-c2)));
                    v = fmaxf(v, g);
                }
            }
            v = fmaxf(v, __shfl_xor(v, 16));
            v = fmaxf(v, __shfl_xor(v, 32));
            if (lane < 16) {
                int P = (mt << 3) + (wave << 1) + ph;     // global patch id
                out[(size_t)P * 128 + (nt << 5) + (nf << 4) + nl] = v;
            }
        }
    }
}

// ---------------------------------------------------------------------------
extern "C" void kernel_launch(void* const* d_in, const int* in_sizes, int n_in,
                              void* d_out, int out_size, void* d_ws, size_t ws_size,
                              hipStream_t stream) {
    const int*   x   = (const int*)d_in[0];
    const float* emb = (const float*)d_in[1];
    const float* w1  = (const float*)d_in[2];
    const float* b1  = (const float*)d_in[3];
    const float* w2  = (const float*)d_in[4];
    const float* b2  = (const float*)d_in[5];
    float* out = (float*)d_out;

    char* ws = (char*)d_ws;
    __bf16* Wp   = (__bf16*)(ws + WS_WP_OFF);
    __bf16* embp = (__bf16*)(ws + WS_EMB_OFF);

    prep_kernel<<<129, 256, 0, stream>>>(w1, w2, emb, (uint4*)Wp, embp);
    gemm_kernel<<<256, 256, 0, stream>>>(x, Wp, (const uint4*)embp, b1, b2, out);
}

// Round 2
// 115.100 us; speedup vs baseline: 1.0932x; 1.0932x over previous
//
#include <hip/hip_runtime.h>
#include <hip/hip_bf16.h>
#include <math.h>

// Dims: B=8, T=1048576, V=257, E=8, C=128, K=512, S=512, N=64
// GEMM view: M=16384, Kdim=4096, Ncols=256.
// Fully fused: col tile nt = [w1 ch 32nt..+32 | w2 ch 32nt..+32] so each lane
// holds matching (c1,c2) accumulators; epilogue does bias+gate+patch-max
// in-register and writes d_out directly. No Cbuf, no reduce kernel.
// R2: BM=128 (grid 512 = 2 blocks/CU) so a second block's MFMA hides the
// per-step barrier vmcnt-drain of the staging loads (1 block/CU exposed it:
// MfmaUtil 24%, 55us).

typedef __bf16 bf16x8 __attribute__((ext_vector_type(8)));
typedef float  f32x4  __attribute__((ext_vector_type(4)));

// ---------------- ws layout ----------------
// [0, 2MB)    : Wp bf16 [nt=4][s'=16][t=8][q=4][n=64][e=8]  (byte = s'*32+q*8+t)
// [2MB, +8KB) : emb bf16 [257][8]
#define WS_WP_OFF   0
#define WS_EMB_OFF  (2u << 20)

__device__ __forceinline__ void load_lds16(const void* g, void* l) {
    __builtin_amdgcn_global_load_lds(
        (const __attribute__((address_space(1))) void*)g,
        (__attribute__((address_space(3))) void*)l,
        16, 0, 0);
}

// ---------------------------------------------------------------------------
// prep: coalesced LDS-transpose weight pack + emb bf16 table.
// cb = nt*2 + nhalf: nhalf=0 -> w1 channels [32nt,32nt+32), nhalf=1 -> w2 same.
// ---------------------------------------------------------------------------
__global__ void prep_kernel(const float* __restrict__ w1,
                            const float* __restrict__ w2,
                            const float* __restrict__ emb,
                            uint4* __restrict__ Wp4,
                            __bf16* __restrict__ embp) {
    int bid = blockIdx.x;
    int tid = threadIdx.x;
    if (bid < 128) {
        __shared__ __bf16 lds[8192];   // [(q*8+t)*32 + cl]*8 + e
        int cb = bid & 7;
        int sB = bid >> 3;
        int nt = cb >> 1, nhalf = cb & 1;
        const float* wsrc = (nhalf ? w2 : w1) + ((size_t)(nt << 5) << 12);
        int j4  = tid & 7;
        int pr0 = tid >> 3;
#pragma unroll
        for (int p = 0; p < 8; ++p) {
            int pair = p * 32 + pr0;          // 0..255 = (cl, e)
            int cl = pair >> 3, e = pair & 7;
            const float4 v = *(const float4*)(wsrc + ((size_t)cl << 12) + (e << 9) + (sB << 5) + (j4 << 2));
            float vv[4] = {v.x, v.y, v.z, v.w};
#pragma unroll
            for (int jj = 0; jj < 4; ++jj) {
                int j = (j4 << 2) + jj;        // byte_local
                int qq = j >> 3, tt = j & 7;
                lds[(((qq << 3) + tt) * 32 + cl) * 8 + e] = (__bf16)vv[jj];
            }
        }
        __syncthreads();
        const uint4* l4 = (const uint4*)lds;
        int base = (nt << 15) + (sB << 11) + (nhalf << 5);   // uint4 units
#pragma unroll
        for (int it = 0; it < 4; ++it) {
            int idx = it * 256 + tid;                         // 0..1023
            int qq = idx >> 8, tt = (idx >> 5) & 7, w = idx & 31;
            Wp4[base + (tt << 8) + (qq << 6) + w] = l4[idx];
        }
    } else {
        for (int i = tid; i < 2056; i += 256) embp[i] = (__bf16)emb[i];
    }
}

// ---------------------------------------------------------------------------
// gemm+epilogue: BM=128, BN=64, 4 waves, wave-tile 32x64 (2rg x 4nf), full K
// (16 steps). Double-buffered B staging (global_load_lds w=16), x prefetch,
// emb in LDS. One wave = one patch (32 rows). Epilogue: bias+gate, in-register
// max over (rg,i), shfl_xor 16/32 across q-groups, direct out write.
// Grid 512 = 128 mt x 4 nt; the 4 nt-blocks sharing an x panel have equal
// bid%8 -> same XCD (L2 dedup of the 4x x re-read).
// ---------------------------------------------------------------------------
__global__ __launch_bounds__(256, 2)
void gemm_kernel(const int* __restrict__ x,
                 const __bf16* __restrict__ Wp,
                 const uint4* __restrict__ embp,
                 const float* __restrict__ b1,
                 const float* __restrict__ b2,
                 float* __restrict__ out) {
    __shared__ uint4 ldsB[2][2048];   // 2 x 32KB: [t=8][q=4][n=64][e=8]
    __shared__ uint4 embl[257];

    const int tid  = threadIdx.x;
    const int wave = tid >> 6;
    const int lane = tid & 63;
    const int q    = lane >> 4;
    const int nl   = lane & 15;

    for (int i = tid; i < 257; i += 256) embl[i] = embp[i];

    const int bid = blockIdx.x;
    const int mt = ((bid >> 5) << 3) | (bid & 7);   // 0..127
    const int nt = (bid >> 3) & 3;
    const int m0 = mt << 7;
    const int rA = m0 + (wave << 5) + nl;
    const char* WpBase = (const char*)Wp + ((size_t)nt << 19);

    const int* xp[2];
#pragma unroll
    for (int rg = 0; rg < 2; ++rg)
        xp[rg] = x + (size_t)(rA + (rg << 4)) * 512 + (q << 3);

    int4 xc[2][2];
#pragma unroll
    for (int rg = 0; rg < 2; ++rg) {
        xc[rg][0] = *(const int4*)xp[rg];
        xc[rg][1] = *(const int4*)(xp[rg] + 4);
    }
    {
        const char* src = WpBase + tid * 16;
        char* dst = (char*)&ldsB[0][0] + tid * 16;
#pragma unroll
        for (int i = 0; i < 8; ++i) load_lds16(src + i * 4096, dst + i * 4096);
    }
    __syncthreads();

    f32x4 acc[2][4] = {};

    for (int sp = 0; sp < 16; ++sp) {
        const int buf = sp & 1;
        if (sp + 1 < 16) {   // stage next step into other buffer (async)
            const char* src = WpBase + ((size_t)(sp + 1) << 15) + tid * 16;
            char* dst = (char*)&ldsB[buf ^ 1][0] + tid * 16;
#pragma unroll
            for (int i = 0; i < 8; ++i) load_lds16(src + i * 4096, dst + i * 4096);
        }
        int idx[2][8];
#pragma unroll
        for (int rg = 0; rg < 2; ++rg) {
            idx[rg][0] = xc[rg][0].x; idx[rg][1] = xc[rg][0].y;
            idx[rg][2] = xc[rg][0].z; idx[rg][3] = xc[rg][0].w;
            idx[rg][4] = xc[rg][1].x; idx[rg][5] = xc[rg][1].y;
            idx[rg][6] = xc[rg][1].z; idx[rg][7] = xc[rg][1].w;
        }
        const int spn = (sp + 1 < 16) ? sp + 1 : sp;   // x prefetch
#pragma unroll
        for (int rg = 0; rg < 2; ++rg) {
            const int* p = xp[rg] + (spn << 5);
            xc[rg][0] = *(const int4*)p;
            xc[rg][1] = *(const int4*)(p + 4);
        }
        const char* Bbase = (const char*)&ldsB[buf][0] + (q << 10) + (nl << 4);
#pragma unroll
        for (int t = 0; t < 8; ++t) {
            bf16x8 a[2];
#pragma unroll
            for (int rg = 0; rg < 2; ++rg)
                a[rg] = *reinterpret_cast<const bf16x8*>(&embl[idx[rg][t]]);
#pragma unroll
            for (int nf = 0; nf < 4; ++nf) {
                bf16x8 b = *reinterpret_cast<const bf16x8*>(Bbase + (t << 12) + (nf << 8));
#pragma unroll
                for (int rg = 0; rg < 2; ++rg)
                    acc[rg][nf] = __builtin_amdgcn_mfma_f32_16x16x32_bf16(a[rg], b, acc[rg][nf], 0, 0, 0);
            }
        }
        __syncthreads();
    }

    // ---- fused epilogue ----
    // acc[rg][nf][i]: row = m0 + wave*32 + rg*16 + q*4 + i
    //   nf in {0,1}: c1 of channel ch = nt*32 + nf*16 + nl; nf+2: c2 of same ch.
    // patch (32 rows) = one wave's tile: P = mt*4 + wave.
    float bb1[2], bb2[2];
#pragma unroll
    for (int nf = 0; nf < 2; ++nf) {
        int ch = (nt << 5) + (nf << 4) + nl;
        bb1[nf] = b1[ch];
        bb2[nf] = b2[ch];
    }
#pragma unroll
    for (int nf = 0; nf < 2; ++nf) {
        float v = -INFINITY;
#pragma unroll
        for (int rg = 0; rg < 2; ++rg) {
#pragma unroll
            for (int i = 0; i < 4; ++i) {
                float c1 = acc[rg][nf][i] + bb1[nf];
                float c2 = acc[rg][nf + 2][i] + bb2[nf];
                float g = c1 * (1.0f / (1.0f + __expf(-c2)));
                v = fmaxf(v, g);
            }
        }
        v = fmaxf(v, __shfl_xor(v, 16));
        v = fmaxf(v, __shfl_xor(v, 32));
        if (lane < 16) {
            int P = (mt << 2) + wave;                 // global patch id
            out[(size_t)P * 128 + (nt << 5) + (nf << 4) + nl] = v;
        }
    }
}

// ---------------------------------------------------------------------------
extern "C" void kernel_launch(void* const* d_in, const int* in_sizes, int n_in,
                              void* d_out, int out_size, void* d_ws, size_t ws_size,
                              hipStream_t stream) {
    const int*   x   = (const int*)d_in[0];
    const float* emb = (const float*)d_in[1];
    const float* w1  = (const float*)d_in[2];
    const float* b1  = (const float*)d_in[3];
    const float* w2  = (const float*)d_in[4];
    const float* b2  = (const float*)d_in[5];
    float* out = (float*)d_out;

    char* ws = (char*)d_ws;
    __bf16* Wp   = (__bf16*)(ws + WS_WP_OFF);
    __bf16* embp = (__bf16*)(ws + WS_EMB_OFF);

    prep_kernel<<<129, 256, 0, stream>>>(w1, w2, emb, (uint4*)Wp, embp);
    gemm_kernel<<<512, 256, 0, stream>>>(x, Wp, (const uint4*)embp, b1, b2, out);
}